// Round 1
// baseline (257.634 us; speedup 1.0000x reference)
//
#include <hip/hip_runtime.h>
#include <stdint.h>

#define NB 16
#define LQ 2048
#define LK 2048
#define DH 64
#define QT 32

typedef short bf16x8 __attribute__((ext_vector_type(8)));
typedef float f32x4 __attribute__((ext_vector_type(4)));

__device__ __forceinline__ unsigned short f2bf(float f) {
    union { float f; uint32_t u; } v; v.f = f;
    uint32_t u = v.u;
    u += 0x7FFFu + ((u >> 16) & 1u);   // RNE; inputs are finite/bounded
    return (unsigned short)(u >> 16);
}
__device__ __forceinline__ float bf2f(unsigned short h) {
    union { uint32_t u; float f; } v; v.u = ((uint32_t)h) << 16;
    return v.f;
}
__device__ __forceinline__ uint32_t pack2(float lo, float hi) {
    return (uint32_t)f2bf(lo) | ((uint32_t)f2bf(hi) << 16);
}

// ---------------- pre-pass: f32 -> bf16 (Q, K) and f32 -> bf16 transposed (V) ----
__global__ void convert_kernel(const float* __restrict__ q, const float* __restrict__ k,
                               const float* __restrict__ v,
                               unsigned short* __restrict__ qb,
                               unsigned short* __restrict__ kb,
                               unsigned short* __restrict__ vtb) {
    int bid = blockIdx.x;
    int tid = threadIdx.x;
    if (bid < 2048) {
        // flat convert: blocks 0..1023 -> q, 1024..2047 -> k ; 2048 elts / block
        const float* src = (bid < 1024) ? q : k;
        unsigned short* dst = (bid < 1024) ? qb : kb;
        int64_t off = (int64_t)(bid & 1023) * 2048 + (int64_t)tid * 8;
        float4 a = *(const float4*)(src + off);
        float4 b4 = *(const float4*)(src + off + 4);
        uint4 o;
        o.x = pack2(a.x, a.y);
        o.y = pack2(a.z, a.w);
        o.z = pack2(b4.x, b4.y);
        o.w = pack2(b4.z, b4.w);
        *(uint4*)(dst + off) = o;
    } else {
        // transpose V[b][k][d] -> vtb[b][d][k], 64x64 tiles
        __shared__ unsigned short tile[64][72];   // +8 pad vs bank conflicts
        int bid2 = bid - 2048;
        int bb = bid2 >> 5, kt = bid2 & 31;
        int k0 = kt * 64;
        int krow = tid >> 2, dc = (tid & 3) * 16;
        const float* vp = v + ((int64_t)(bb * LK) + k0 + krow) * DH + dc;
        float4 x0 = *(const float4*)(vp);
        float4 x1 = *(const float4*)(vp + 4);
        float4 x2 = *(const float4*)(vp + 8);
        float4 x3 = *(const float4*)(vp + 12);
        float vals[16] = {x0.x, x0.y, x0.z, x0.w, x1.x, x1.y, x1.z, x1.w,
                          x2.x, x2.y, x2.z, x2.w, x3.x, x3.y, x3.z, x3.w};
        #pragma unroll
        for (int i = 0; i < 16; ++i) tile[dc + i][krow] = f2bf(vals[i]);
        __syncthreads();
        int d = tid >> 2, kc = (tid & 3) * 16;
        uint4 r0 = *(const uint4*)&tile[d][kc];
        uint4 r1 = *(const uint4*)&tile[d][kc + 8];
        unsigned short* op = vtb + ((int64_t)(bb * DH) + d) * LK + k0 + kc;
        *(uint4*)op = r0;
        *(uint4*)(op + 8) = r1;
    }
}

// ---------------- fused attention ------------------------------------------------
// grid 1024 (16 batches x 64 q-tiles), 512 threads (8 waves), QT=32 rows/block.
// LDS: e[32][2048] bf16 (XOR-swizzled rows) + denom_part[4][32] f32 = 131584 B.
__launch_bounds__(512, 1)
__global__ void attn_kernel(const unsigned short* __restrict__ qb,
                            const unsigned short* __restrict__ kb,
                            const unsigned short* __restrict__ vtb,
                            const float* __restrict__ mask,
                            float* __restrict__ out, float* __restrict__ attn) {
    extern __shared__ char smem[];
    float* denom_part = (float*)(smem + QT * LK * 2);   // [4][32]

    int bid = blockIdx.x;
    int swz = (bid & 7) * 128 + (bid >> 3);   // bijective XCD swizzle (1024 % 8 == 0)
    int b = swz >> 6;
    int q0 = (swz & 63) * QT;

    int tid = threadIdx.x;
    int lane = tid & 63;
    int wave = tid >> 6;
    int wm = wave >> 2, wn = wave & 3;        // wave tile: rows wm*16, cols wn*16
    int lr = lane & 15, lg = lane >> 4;

    // Q A-fragments (held in registers the whole kernel)
    // A layout (16x16x32): lane holds A[row=lane%16][k = 8*(lane/16)+i]
    bf16x8 qf0, qf1;
    {
        const unsigned short* qp = qb + ((int64_t)(b * LQ + q0 + wm * 16 + lr)) * DH + 8 * lg;
        qf0 = *(const bf16x8*)qp;
        qf1 = *(const bf16x8*)(qp + 32);
    }

    float dsum[4] = {0.f, 0.f, 0.f, 0.f};

    // ---- phase 1: S = clamp(QK^T/8), e = exp(x*m)*m -> LDS ; no barriers ----
    for (int kt = 0; kt < LK / 64; ++kt) {
        int kbase = kt * 64 + wn * 16;
        const unsigned short* kp = kb + ((int64_t)(b * LK + kbase + lr)) * DH + 8 * lg;
        bf16x8 kf0 = *(const bf16x8*)kp;
        bf16x8 kf1 = *(const bf16x8*)(kp + 32);
        f32x4 acc = {0.f, 0.f, 0.f, 0.f};
        acc = __builtin_amdgcn_mfma_f32_16x16x32_bf16(qf0, kf0, acc, 0, 0, 0);
        acc = __builtin_amdgcn_mfma_f32_16x16x32_bf16(qf1, kf1, acc, 0, 0, 0);
        // C layout: col = lane&15 (key), row = (lane>>4)*4 + reg (q-row)
        int c = kbase + lr;
        const float* mp = mask + ((int64_t)(b * LQ + q0 + wm * 16 + lg * 4)) * LK + c;
        #pragma unroll
        for (int j = 0; j < 4; ++j) {
            int r = wm * 16 + lg * 4 + j;
            float s = acc[j] * 0.125f;
            s = fminf(fmaxf(s, -15.0f), 15.0f);
            float m = mp[(int64_t)j * LK];
            float e = __expf(s * m) * m;       // no max-subtract: x<=15, error ~eps
            unsigned short eb = f2bf(e);
            dsum[j] += bf2f(eb);               // sum the rounded value (consistency)
            int byteoff = (r * 4096 + c * 2) ^ ((r & 7) << 4);   // bank swizzle
            *(unsigned short*)(smem + byteoff) = eb;
        }
    }

    // ---- row-sum reduction: 16 lanes (cols) then 4 waves (wn) via LDS ----
    #pragma unroll
    for (int j = 0; j < 4; ++j) {
        float s = dsum[j];
        s += __shfl_xor(s, 1);
        s += __shfl_xor(s, 2);
        s += __shfl_xor(s, 4);
        s += __shfl_xor(s, 8);
        if (lr == 0) denom_part[wn * 32 + wm * 16 + lg * 4 + j] = s;
    }
    __syncthreads();   // the only barrier

    // ---- phase 2: PV from LDS e (A) and global V^T (B) ----
    f32x4 pacc = {0.f, 0.f, 0.f, 0.f};
    {
        const unsigned short* vp = vtb + ((int64_t)(b * DH + wn * 16 + lr)) * LK + 8 * lg;
        int r = wm * 16 + lr;
        int rowoff = r * 4096;
        int sw = (r & 7) << 4;
        for (int kk = 0; kk < LK; kk += 32) {
            int byteoff = (rowoff + (kk + 8 * lg) * 2) ^ sw;
            bf16x8 ef = *(const bf16x8*)(smem + byteoff);
            bf16x8 vf = *(const bf16x8*)(vp + kk);
            pacc = __builtin_amdgcn_mfma_f32_16x16x32_bf16(ef, vf, pacc, 0, 0, 0);
        }
    }

    // ---- out write: out[r][wn*16+lr] = pacc/denom ----
    #pragma unroll
    for (int j = 0; j < 4; ++j) {
        int r = wm * 16 + lg * 4 + j;
        float den = denom_part[r] + denom_part[32 + r] + denom_part[64 + r] +
                    denom_part[96 + r] + 1e-6f;
        out[((int64_t)(b * LQ + q0 + r)) * DH + wn * 16 + lr] = pacc[j] / den;
    }

    // ---- phase 3: attn write-out, coalesced 512B bursts per 16-thread group ----
    {
        int r = tid >> 4;
        float den = denom_part[r] + denom_part[32 + r] + denom_part[64 + r] +
                    denom_part[96 + r] + 1e-6f;
        float inv = 1.0f / den;
        float* ap = attn + ((int64_t)(b * LQ + q0 + r)) * LK;
        int rowoff = r * 4096;
        int sw = (r & 7) << 4;
        for (int c0 = (tid & 15) * 8; c0 < LK; c0 += 128) {
            int byteoff = (rowoff + c0 * 2) ^ sw;
            bf16x8 ev = *(const bf16x8*)(smem + byteoff);
            float4 o0, o1;
            o0.x = bf2f((unsigned short)ev[0]) * inv;
            o0.y = bf2f((unsigned short)ev[1]) * inv;
            o0.z = bf2f((unsigned short)ev[2]) * inv;
            o0.w = bf2f((unsigned short)ev[3]) * inv;
            o1.x = bf2f((unsigned short)ev[4]) * inv;
            o1.y = bf2f((unsigned short)ev[5]) * inv;
            o1.z = bf2f((unsigned short)ev[6]) * inv;
            o1.w = bf2f((unsigned short)ev[7]) * inv;
            *(float4*)(ap + c0) = o0;
            *(float4*)(ap + c0 + 4) = o1;
        }
    }
}

extern "C" void kernel_launch(void* const* d_in, const int* in_sizes, int n_in,
                              void* d_out, int out_size, void* d_ws, size_t ws_size,
                              hipStream_t stream) {
    const float* q    = (const float*)d_in[0];
    const float* k    = (const float*)d_in[1];
    const float* v    = (const float*)d_in[2];
    const float* mask = (const float*)d_in[3];
    float* out  = (float*)d_out;
    float* attn = out + (int64_t)NB * LQ * DH;   // outputs concatenated flat

    unsigned short* qb  = (unsigned short*)d_ws;
    unsigned short* kb  = qb + (int64_t)NB * LQ * DH;
    unsigned short* vtb = kb + (int64_t)NB * LK * DH;   // 12 MB total scratch

    (void)hipFuncSetAttribute((const void*)attn_kernel,
                              hipFuncAttributeMaxDynamicSharedMemorySize, 131584);

    convert_kernel<<<2560, 256, 0, stream>>>(q, k, v, qb, kb, vtb);
    attn_kernel<<<1024, 512, 131584, stream>>>(qb, kb, vtb, mask, out, attn);
}

// Round 2
// 236.304 us; speedup vs baseline: 1.0903x; 1.0903x over previous
//
#include <hip/hip_runtime.h>
#include <stdint.h>

#define NB 16
#define LQ 2048
#define LK 2048
#define DH 64
#define QT 16

typedef short bf16x8 __attribute__((ext_vector_type(8)));
typedef float f32x4 __attribute__((ext_vector_type(4)));

__device__ __forceinline__ unsigned short f2bf(float f) {
    union { float f; uint32_t u; } v; v.f = f;
    uint32_t u = v.u;
    u += 0x7FFFu + ((u >> 16) & 1u);   // RNE; inputs are finite/bounded
    return (unsigned short)(u >> 16);
}
__device__ __forceinline__ float bf2f(unsigned short h) {
    union { uint32_t u; float f; } v; v.u = ((uint32_t)h) << 16;
    return v.f;
}
__device__ __forceinline__ uint32_t pack2(float lo, float hi) {
    return (uint32_t)f2bf(lo) | ((uint32_t)f2bf(hi) << 16);
}

// ---------------- pre-pass: f32 -> bf16 (Q, K) and f32 -> bf16 transposed (V) ----
__global__ void convert_kernel(const float* __restrict__ q, const float* __restrict__ k,
                               const float* __restrict__ v,
                               unsigned short* __restrict__ qb,
                               unsigned short* __restrict__ kb,
                               unsigned short* __restrict__ vtb) {
    int bid = blockIdx.x;
    int tid = threadIdx.x;
    if (bid < 2048) {
        const float* src = (bid < 1024) ? q : k;
        unsigned short* dst = (bid < 1024) ? qb : kb;
        int64_t off = (int64_t)(bid & 1023) * 2048 + (int64_t)tid * 8;
        float4 a = *(const float4*)(src + off);
        float4 b4 = *(const float4*)(src + off + 4);
        uint4 o;
        o.x = pack2(a.x, a.y);
        o.y = pack2(a.z, a.w);
        o.z = pack2(b4.x, b4.y);
        o.w = pack2(b4.z, b4.w);
        *(uint4*)(dst + off) = o;
    } else {
        // transpose V[b][k][d] -> vtb[b][d][k], 64x64 tiles
        __shared__ unsigned short tile[64][72];
        int bid2 = bid - 2048;
        int bb = bid2 >> 5, kt = bid2 & 31;
        int k0 = kt * 64;
        int krow = tid >> 2, dc = (tid & 3) * 16;
        const float* vp = v + ((int64_t)(bb * LK) + k0 + krow) * DH + dc;
        float4 x0 = *(const float4*)(vp);
        float4 x1 = *(const float4*)(vp + 4);
        float4 x2 = *(const float4*)(vp + 8);
        float4 x3 = *(const float4*)(vp + 12);
        float vals[16] = {x0.x, x0.y, x0.z, x0.w, x1.x, x1.y, x1.z, x1.w,
                          x2.x, x2.y, x2.z, x2.w, x3.x, x3.y, x3.z, x3.w};
        #pragma unroll
        for (int i = 0; i < 16; ++i) tile[dc + i][krow] = f2bf(vals[i]);
        __syncthreads();
        int d = tid >> 2, kc = (tid & 3) * 16;
        uint4 r0 = *(const uint4*)&tile[d][kc];
        uint4 r1 = *(const uint4*)&tile[d][kc + 8];
        unsigned short* op = vtb + ((int64_t)(bb * DH) + d) * LK + k0 + kc;
        *(uint4*)op = r0;
        *(uint4*)(op + 8) = r1;
    }
}

// ---------------- fused attention ------------------------------------------------
// grid 2048 (16 batches x 128 q-tiles), 512 threads (8 waves), QT=16 rows/block.
// LDS: e[16][2048] bf16 (XOR-swizzled) 65536 + denom[8][16] f32 512 + pp[4][16][16]
// f32 4096 = 70144 B  ->  2 blocks/CU, 16 waves/CU.
__launch_bounds__(512, 4)
__global__ void attn_kernel(const unsigned short* __restrict__ qb,
                            const unsigned short* __restrict__ kb,
                            const unsigned short* __restrict__ vtb,
                            const float* __restrict__ mask,
                            float* __restrict__ out, float* __restrict__ attn) {
    extern __shared__ char smem[];
    float* denom_part = (float*)(smem + QT * LK * 2);            // [8][16]
    float* pp         = (float*)(smem + QT * LK * 2 + 512);      // [4][16][16]

    int bid = blockIdx.x;
    int swz = (bid & 7) * 256 + (bid >> 3);   // bijective XCD swizzle (2048 % 8 == 0)
    int b = swz >> 7;
    int q0 = (swz & 127) * QT;

    int tid = threadIdx.x;
    int lane = tid & 63;
    int wave = tid >> 6;                      // phase 1: wave = column-tile index wn
    int lr = lane & 15, lg = lane >> 4;

    // Q A-fragments: A[row=lane%16][k=8*(lane/16)+i]; rows q0..q0+15 for all waves
    bf16x8 qf0, qf1;
    {
        const unsigned short* qp = qb + ((int64_t)(b * LQ + q0 + lr)) * DH + 8 * lg;
        qf0 = *(const bf16x8*)qp;
        qf1 = *(const bf16x8*)(qp + 32);
    }

    float dsum[4] = {0.f, 0.f, 0.f, 0.f};

    // ---- phase 1: e = exp(clamp(QK^T/8)*m)*m -> LDS ; 1-deep SW pipeline ----
    {
        const int64_t krow0 = (int64_t)b * LK;
        const float* mbase = mask + ((int64_t)(b * LQ + q0 + lg * 4)) * LK;
        bf16x8 kf0, kf1;
        float mr0, mr1, mr2, mr3;
        {
            const unsigned short* kp =
                kb + (krow0 + wave * 16 + lr) * DH + 8 * lg;
            kf0 = *(const bf16x8*)kp;
            kf1 = *(const bf16x8*)(kp + 32);
            const float* mp = mbase + wave * 16 + lr;
            mr0 = mp[0]; mr1 = mp[LK]; mr2 = mp[2 * LK]; mr3 = mp[3 * LK];
        }
        for (int kt = 0; kt < LK / 128; ++kt) {
            bf16x8 nk0, nk1;
            float nm0, nm1, nm2, nm3;
            if (kt < LK / 128 - 1) {
                int nbase = (kt + 1) * 128 + wave * 16;
                const unsigned short* kp = kb + (krow0 + nbase + lr) * DH + 8 * lg;
                nk0 = *(const bf16x8*)kp;
                nk1 = *(const bf16x8*)(kp + 32);
                const float* mp = mbase + nbase + lr;
                nm0 = mp[0]; nm1 = mp[LK]; nm2 = mp[2 * LK]; nm3 = mp[3 * LK];
            }
            f32x4 acc = {0.f, 0.f, 0.f, 0.f};
            acc = __builtin_amdgcn_mfma_f32_16x16x32_bf16(qf0, kf0, acc, 0, 0, 0);
            acc = __builtin_amdgcn_mfma_f32_16x16x32_bf16(qf1, kf1, acc, 0, 0, 0);
            int c = kt * 128 + wave * 16 + lr;
            float mv[4] = {mr0, mr1, mr2, mr3};
            #pragma unroll
            for (int j = 0; j < 4; ++j) {
                int r = lg * 4 + j;
                float s = acc[j] * 0.125f;
                s = fminf(fmaxf(s, -15.0f), 15.0f);
                float m = mv[j];
                float e = __expf(s * m) * m;
                unsigned short eb = f2bf(e);
                dsum[j] += bf2f(eb);
                int byteoff = (r * 4096 + c * 2) ^ ((r & 7) << 4);
                *(unsigned short*)(smem + byteoff) = eb;
            }
            kf0 = nk0; kf1 = nk1;
            mr0 = nm0; mr1 = nm1; mr2 = nm2; mr3 = nm3;
        }
    }

    // ---- row-sum partials: reduce 16 cols per wave, stash per-wave partial ----
    #pragma unroll
    for (int j = 0; j < 4; ++j) {
        float s = dsum[j];
        s += __shfl_xor(s, 1);
        s += __shfl_xor(s, 2);
        s += __shfl_xor(s, 4);
        s += __shfl_xor(s, 8);
        if (lr == 0) denom_part[wave * 16 + lg * 4 + j] = s;
    }
    __syncthreads();

    // ---- phase 2: PV, K-split across waves. wave w: cols (w&3)*16, K-half w>>2 ----
    f32x4 pacc = {0.f, 0.f, 0.f, 0.f};
    int cw = (wave & 3) * 16, kh = wave >> 2;
    {
        const unsigned short* vp =
            vtb + ((int64_t)(b * DH + cw + lr)) * LK + kh * 1024 + 8 * lg;
        int rowoff = lr * 4096;
        int sw = (lr & 7) << 4;
        int kk0 = kh * 1024;
        for (int kk = 0; kk < 1024; kk += 32) {
            int byteoff = (rowoff + (kk0 + kk + 8 * lg) * 2) ^ sw;
            bf16x8 ef = *(const bf16x8*)(smem + byteoff);
            bf16x8 vf = *(const bf16x8*)(vp + kk);
            pacc = __builtin_amdgcn_mfma_f32_16x16x32_bf16(ef, vf, pacc, 0, 0, 0);
        }
    }
    if (kh == 1) {
        #pragma unroll
        for (int j = 0; j < 4; ++j)
            pp[(wave & 3) * 256 + (lg * 4 + j) * 16 + lr] = pacc[j];
    }
    __syncthreads();
    if (kh == 0) {
        #pragma unroll
        for (int j = 0; j < 4; ++j) {
            int r = lg * 4 + j;
            float den = 1e-6f;
            #pragma unroll
            for (int w = 0; w < 8; ++w) den += denom_part[w * 16 + r];
            float val = pacc[j] + pp[cw * 16 + r * 16 + lr];
            out[((int64_t)(b * LQ + q0 + r)) * DH + cw + lr] = val / den;
        }
    }

    // ---- phase 3: attn write-out; 32 threads per row, 2048 f32 per row ----
    {
        int r = tid >> 5;
        float den = 1e-6f;
        #pragma unroll
        for (int w = 0; w < 8; ++w) den += denom_part[w * 16 + r];
        float inv = 1.0f / den;
        float* ap = attn + ((int64_t)(b * LQ + q0 + r)) * LK;
        int rowoff = r * 4096;
        int sw = (r & 7) << 4;
        for (int c0 = (tid & 31) * 8; c0 < LK; c0 += 256) {
            int byteoff = (rowoff + c0 * 2) ^ sw;
            bf16x8 ev = *(const bf16x8*)(smem + byteoff);
            float4 o0, o1;
            o0.x = bf2f((unsigned short)ev[0]) * inv;
            o0.y = bf2f((unsigned short)ev[1]) * inv;
            o0.z = bf2f((unsigned short)ev[2]) * inv;
            o0.w = bf2f((unsigned short)ev[3]) * inv;
            o1.x = bf2f((unsigned short)ev[4]) * inv;
            o1.y = bf2f((unsigned short)ev[5]) * inv;
            o1.z = bf2f((unsigned short)ev[6]) * inv;
            o1.w = bf2f((unsigned short)ev[7]) * inv;
            *(float4*)(ap + c0) = o0;
            *(float4*)(ap + c0 + 4) = o1;
        }
    }
}

extern "C" void kernel_launch(void* const* d_in, const int* in_sizes, int n_in,
                              void* d_out, int out_size, void* d_ws, size_t ws_size,
                              hipStream_t stream) {
    const float* q    = (const float*)d_in[0];
    const float* k    = (const float*)d_in[1];
    const float* v    = (const float*)d_in[2];
    const float* mask = (const float*)d_in[3];
    float* out  = (float*)d_out;
    float* attn = out + (int64_t)NB * LQ * DH;

    unsigned short* qb  = (unsigned short*)d_ws;
    unsigned short* kb  = qb + (int64_t)NB * LQ * DH;
    unsigned short* vtb = kb + (int64_t)NB * LK * DH;

    (void)hipFuncSetAttribute((const void*)attn_kernel,
                              hipFuncAttributeMaxDynamicSharedMemorySize, 70144);

    convert_kernel<<<2560, 256, 0, stream>>>(q, k, v, qb, kb, vtb);
    attn_kernel<<<2048, 512, 70144, stream>>>(qb, kb, vtb, mask, out, attn);
}

// Round 3
// 230.794 us; speedup vs baseline: 1.1163x; 1.0239x over previous
//
#include <hip/hip_runtime.h>
#include <stdint.h>

#define NB 16
#define LQ 2048
#define LK 2048
#define DH 64
#define QT 16
#define NW 16                 // waves per block
#define STRIP (NW * 16)       // 256 keys per phase-1 iteration
#define NIT (LK / STRIP)      // 8

typedef short bf16x8 __attribute__((ext_vector_type(8)));
typedef float f32x4 __attribute__((ext_vector_type(4)));

__device__ __forceinline__ unsigned short f2bf(float f) {
    union { float f; uint32_t u; } v; v.f = f;
    uint32_t u = v.u;
    u += 0x7FFFu + ((u >> 16) & 1u);   // RNE; inputs finite/bounded
    return (unsigned short)(u >> 16);
}
__device__ __forceinline__ float bf2f(unsigned short h) {
    union { uint32_t u; float f; } v; v.u = ((uint32_t)h) << 16;
    return v.f;
}
__device__ __forceinline__ uint32_t pack2(float lo, float hi) {
    return (uint32_t)f2bf(lo) | ((uint32_t)f2bf(hi) << 16);
}

// ---------------- pre-pass: f32 -> bf16 (Q, K) and f32 -> bf16 transposed (V) ----
__global__ void convert_kernel(const float* __restrict__ q, const float* __restrict__ k,
                               const float* __restrict__ v,
                               unsigned short* __restrict__ qb,
                               unsigned short* __restrict__ kb,
                               unsigned short* __restrict__ vtb) {
    int bid = blockIdx.x;
    int tid = threadIdx.x;
    if (bid < 2048) {
        const float* src = (bid < 1024) ? q : k;
        unsigned short* dst = (bid < 1024) ? qb : kb;
        int64_t off = (int64_t)(bid & 1023) * 2048 + (int64_t)tid * 8;
        float4 a = *(const float4*)(src + off);
        float4 b4 = *(const float4*)(src + off + 4);
        uint4 o;
        o.x = pack2(a.x, a.y);
        o.y = pack2(a.z, a.w);
        o.z = pack2(b4.x, b4.y);
        o.w = pack2(b4.z, b4.w);
        *(uint4*)(dst + off) = o;
    } else {
        __shared__ unsigned short tile[64][72];
        int bid2 = bid - 2048;
        int bb = bid2 >> 5, kt = bid2 & 31;
        int k0 = kt * 64;
        int krow = tid >> 2, dc = (tid & 3) * 16;
        const float* vp = v + ((int64_t)(bb * LK) + k0 + krow) * DH + dc;
        float4 x0 = *(const float4*)(vp);
        float4 x1 = *(const float4*)(vp + 4);
        float4 x2 = *(const float4*)(vp + 8);
        float4 x3 = *(const float4*)(vp + 12);
        float vals[16] = {x0.x, x0.y, x0.z, x0.w, x1.x, x1.y, x1.z, x1.w,
                          x2.x, x2.y, x2.z, x2.w, x3.x, x3.y, x3.z, x3.w};
        #pragma unroll
        for (int i = 0; i < 16; ++i) tile[dc + i][krow] = f2bf(vals[i]);
        __syncthreads();
        int d = tid >> 2, kc = (tid & 3) * 16;
        uint4 r0 = *(const uint4*)&tile[d][kc];
        uint4 r1 = *(const uint4*)&tile[d][kc + 8];
        unsigned short* op = vtb + ((int64_t)(bb * DH) + d) * LK + k0 + kc;
        *(uint4*)op = r0;
        *(uint4*)(op + 8) = r1;
    }
}

// ---------------- fused attention ------------------------------------------------
// grid 2048 (16 b x 128 q-tiles), 1024 threads (16 waves), QT=16 rows/block.
// LDS: e[16][2048] bf16 (XOR-swizzled) 65536 + denom[16][16] f32 1024 +
//      pp[12][16][16] f32 12288 = 78848 B -> 2 blocks/CU, 32 waves/CU (100%).
__launch_bounds__(1024, 8)
__global__ void attn_kernel(const unsigned short* __restrict__ qb,
                            const unsigned short* __restrict__ kb,
                            const unsigned short* __restrict__ vtb,
                            const float* __restrict__ mask,
                            float* __restrict__ out, float* __restrict__ attn) {
    extern __shared__ char smem[];
    float* denom_part = (float*)(smem + QT * LK * 2);            // [16][16]
    float* pp         = (float*)(smem + QT * LK * 2 + 1024);     // [12][16][16]

    int bid = blockIdx.x;
    int swz = (bid & 7) * 256 + (bid >> 3);   // bijective XCD swizzle (2048 % 8 == 0)
    int b = swz >> 7;
    int q0 = (swz & 127) * QT;

    int tid = threadIdx.x;
    int lane = tid & 63;
    int wave = tid >> 6;
    int lr = lane & 15, lg = lane >> 4;

    // Q fragments (B-operand of S^T = K·Q^T): lane holds Q[q0+lr][8*lg+i]
    bf16x8 qf0, qf1;
    {
        const unsigned short* qp = qb + ((int64_t)(b * LQ + q0 + lr)) * DH + 8 * lg;
        qf0 = *(const bf16x8*)qp;
        qf1 = *(const bf16x8*)(qp + 32);
    }

    float dsum = 0.f;   // partial row-sum for q-row lr (this wave's keys)

    // ---- phase 1: S^T = K·Q^T; e = exp(clamp(s)*m)*m -> LDS --------------------
    // Lane (lr,lg) of wave w computes keys w*16+lg*4+{0..3} of q-row lr.
    {
        const unsigned short* kpw =
            kb + (int64_t)b * LK * DH + (wave * 16 + lr) * DH + 8 * lg;
        const float* mrow =
            mask + ((int64_t)(b * LQ + q0 + lr)) * LK + wave * 16 + lg * 4;
        float4 mf = *(const float4*)mrow;
        #pragma unroll
        for (int kt = 0; kt < NIT; ++kt) {
            float4 nm;
            if (kt < NIT - 1) nm = *(const float4*)(mrow + (kt + 1) * STRIP);
            bf16x8 kf0 = *(const bf16x8*)(kpw + (int64_t)kt * STRIP * DH);
            bf16x8 kf1 = *(const bf16x8*)(kpw + (int64_t)kt * STRIP * DH + 32);
            f32x4 acc = {0.f, 0.f, 0.f, 0.f};
            acc = __builtin_amdgcn_mfma_f32_16x16x32_bf16(kf0, qf0, acc, 0, 0, 0);
            acc = __builtin_amdgcn_mfma_f32_16x16x32_bf16(kf1, qf1, acc, 0, 0, 0);
            // C[row=lg*4+j][col=lr] = S[q=lr][key = kt*STRIP + wave*16 + lg*4 + j]
            float mv[4] = {mf.x, mf.y, mf.z, mf.w};
            unsigned short eb[4];
            #pragma unroll
            for (int j = 0; j < 4; ++j) {
                float s = acc[j] * 0.125f;
                s = fminf(fmaxf(s, -15.0f), 15.0f);
                float e = __expf(s * mv[j]) * mv[j];
                eb[j] = f2bf(e);
                dsum += bf2f(eb[j]);
            }
            uint2 u;
            u.x = (uint32_t)eb[0] | ((uint32_t)eb[1] << 16);
            u.y = (uint32_t)eb[2] | ((uint32_t)eb[3] << 16);
            int c = kt * STRIP + wave * 16 + lg * 4;
            int byteoff = (lr * 4096 + c * 2) ^ ((lr & 7) << 4);
            *(uint2*)(smem + byteoff) = u;
            mf = nm;
        }
    }

    // ---- row-sum partials: reduce across lg (keys) within wave ----
    {
        float s = dsum;
        s += __shfl_xor(s, 16);
        s += __shfl_xor(s, 32);
        if (lg == 0) denom_part[wave * 16 + lr] = s;
    }
    __syncthreads();

    // ---- phase 2: PV; wave w -> col-tile (w&3)*16, K-quarter w>>2 ----
    f32x4 pacc = {0.f, 0.f, 0.f, 0.f};
    int cw = (wave & 3) * 16, kq = wave >> 2;
    {
        const unsigned short* vp =
            vtb + ((int64_t)(b * DH + cw + lr)) * LK + kq * 512 + 8 * lg;
        int rowbase = lr * 4096;
        int sw = (lr & 7) << 4;
        int kk0 = kq * 512;
        #pragma unroll 4
        for (int kk = 0; kk < 512; kk += 32) {
            int byteoff = (rowbase + (kk0 + kk + 8 * lg) * 2) ^ sw;
            bf16x8 ef = *(const bf16x8*)(smem + byteoff);
            bf16x8 vf = *(const bf16x8*)(vp + kk);
            pacc = __builtin_amdgcn_mfma_f32_16x16x32_bf16(ef, vf, pacc, 0, 0, 0);
        }
    }
    if (kq != 0) {
        #pragma unroll
        for (int j = 0; j < 4; ++j)
            pp[((kq - 1) * 4 + (wave & 3)) * 256 + (lg * 4 + j) * 16 + lr] = pacc[j];
    }
    __syncthreads();
    if (kq == 0) {
        int c4 = wave & 3;
        #pragma unroll
        for (int j = 0; j < 4; ++j) {
            int r = lg * 4 + j;
            float den = 1e-6f;
            #pragma unroll
            for (int w = 0; w < NW; ++w) den += denom_part[w * 16 + r];
            float val = pacc[j] + pp[(c4)*256 + r * 16 + lr] +
                        pp[(4 + c4) * 256 + r * 16 + lr] +
                        pp[(8 + c4) * 256 + r * 16 + lr];
            out[((int64_t)(b * LQ + q0 + r)) * DH + cw + lr] = val / den;
        }
    }

    // ---- phase 3: attn write-out; 64 threads per row ----
    {
        int r = tid >> 6;
        float den = 1e-6f;
        #pragma unroll
        for (int w = 0; w < NW; ++w) den += denom_part[w * 16 + r];
        float inv = 1.0f / den;
        float* ap = attn + ((int64_t)(b * LQ + q0 + r)) * LK;
        int rowbase = r * 4096;
        int sw = (r & 7) << 4;
        #pragma unroll
        for (int c0 = (tid & 63) * 8; c0 < LK; c0 += 512) {
            int byteoff = (rowbase + c0 * 2) ^ sw;
            bf16x8 ev = *(const bf16x8*)(smem + byteoff);
            float4 o0, o1;
            o0.x = bf2f((unsigned short)ev[0]) * inv;
            o0.y = bf2f((unsigned short)ev[1]) * inv;
            o0.z = bf2f((unsigned short)ev[2]) * inv;
            o0.w = bf2f((unsigned short)ev[3]) * inv;
            o1.x = bf2f((unsigned short)ev[4]) * inv;
            o1.y = bf2f((unsigned short)ev[5]) * inv;
            o1.z = bf2f((unsigned short)ev[6]) * inv;
            o1.w = bf2f((unsigned short)ev[7]) * inv;
            *(float4*)(ap + c0) = o0;
            *(float4*)(ap + c0 + 4) = o1;
        }
    }
}

extern "C" void kernel_launch(void* const* d_in, const int* in_sizes, int n_in,
                              void* d_out, int out_size, void* d_ws, size_t ws_size,
                              hipStream_t stream) {
    const float* q    = (const float*)d_in[0];
    const float* k    = (const float*)d_in[1];
    const float* v    = (const float*)d_in[2];
    const float* mask = (const float*)d_in[3];
    float* out  = (float*)d_out;
    float* attn = out + (int64_t)NB * LQ * DH;

    unsigned short* qb  = (unsigned short*)d_ws;
    unsigned short* kb  = qb + (int64_t)NB * LQ * DH;
    unsigned short* vtb = kb + (int64_t)NB * LK * DH;

    (void)hipFuncSetAttribute((const void*)attn_kernel,
                              hipFuncAttributeMaxDynamicSharedMemorySize, 78848);

    convert_kernel<<<2560, 256, 0, stream>>>(q, k, v, qb, kb, vtb);
    attn_kernel<<<2048, 1024, 78848, stream>>>(qb, kb, vtb, mask, out, attn);
}

// Round 5
// 209.689 us; speedup vs baseline: 1.2286x; 1.1007x over previous
//
#include <hip/hip_runtime.h>
#include <stdint.h>

#define NB 16
#define LQ 2048
#define LK 2048
#define DH 64
#define QT 16
#define NW 16                 // waves per block
#define STRIP (NW * 16)       // 256 keys per phase-1 iteration
#define NIT (LK / STRIP)      // 8

typedef short bf16x8 __attribute__((ext_vector_type(8)));
typedef float f32x4 __attribute__((ext_vector_type(4)));

__device__ __forceinline__ unsigned short f2bf(float f) {
    union { float f; uint32_t u; } v; v.f = f;
    uint32_t u = v.u;
    u += 0x7FFFu + ((u >> 16) & 1u);   // RNE; inputs finite/bounded
    return (unsigned short)(u >> 16);
}
__device__ __forceinline__ float bf2f(unsigned short h) {
    union { uint32_t u; float f; } v; v.u = ((uint32_t)h) << 16;
    return v.f;
}
__device__ __forceinline__ uint32_t pack2(float lo, float hi) {
    return (uint32_t)f2bf(lo) | ((uint32_t)f2bf(hi) << 16);
}

// ---------------- pre-pass: f32 -> bf16 (Q, K) and f32 -> bf16 transposed (V) ----
__global__ void convert_kernel(const float* __restrict__ q, const float* __restrict__ k,
                               const float* __restrict__ v,
                               unsigned short* __restrict__ qb,
                               unsigned short* __restrict__ kb,
                               unsigned short* __restrict__ vtb) {
    int bid = blockIdx.x;
    int tid = threadIdx.x;
    if (bid < 2048) {
        const float* src = (bid < 1024) ? q : k;
        unsigned short* dst = (bid < 1024) ? qb : kb;
        int64_t off = (int64_t)(bid & 1023) * 2048 + (int64_t)tid * 8;
        float4 a = *(const float4*)(src + off);
        float4 b4 = *(const float4*)(src + off + 4);
        uint4 o;
        o.x = pack2(a.x, a.y);
        o.y = pack2(a.z, a.w);
        o.z = pack2(b4.x, b4.y);
        o.w = pack2(b4.z, b4.w);
        *(uint4*)(dst + off) = o;
    } else {
        __shared__ unsigned short tile[64][72];
        int bid2 = bid - 2048;
        int bb = bid2 >> 5, kt = bid2 & 31;
        int k0 = kt * 64;
        int krow = tid >> 2, dc = (tid & 3) * 16;
        const float* vp = v + ((int64_t)(bb * LK) + k0 + krow) * DH + dc;
        float4 x0 = *(const float4*)(vp);
        float4 x1 = *(const float4*)(vp + 4);
        float4 x2 = *(const float4*)(vp + 8);
        float4 x3 = *(const float4*)(vp + 12);
        float vals[16] = {x0.x, x0.y, x0.z, x0.w, x1.x, x1.y, x1.z, x1.w,
                          x2.x, x2.y, x2.z, x2.w, x3.x, x3.y, x3.z, x3.w};
        #pragma unroll
        for (int i = 0; i < 16; ++i) tile[dc + i][krow] = f2bf(vals[i]);
        __syncthreads();
        int d = tid >> 2, kc = (tid & 3) * 16;
        uint4 r0 = *(const uint4*)&tile[d][kc];
        uint4 r1 = *(const uint4*)&tile[d][kc + 8];
        unsigned short* op = vtb + ((int64_t)(bb * DH) + d) * LK + k0 + kc;
        *(uint4*)op = r0;
        *(uint4*)(op + 8) = r1;
    }
}

// ---------------- fused attention ------------------------------------------------
// grid 2048 (16 b x 128 q-tiles), 1024 threads (16 waves), QT=16 rows/block.
// LDS: p/e[16][2048] bf16 (XOR-swizzled) 65536 + den[16] f32 64 + pp[12][16][16]
// f32 12288 = 77888 B -> 2 blocks/CU, 32 waves/CU.
__launch_bounds__(1024, 8)
__global__ void attn_kernel(const unsigned short* __restrict__ qb,
                            const unsigned short* __restrict__ kb,
                            const unsigned short* __restrict__ vtb,
                            const float* __restrict__ mask,
                            float* __restrict__ out, float* __restrict__ attn) {
    extern __shared__ char smem[];
    float* denom_part = (float*)(smem + QT * LK * 2);           // [16]
    float* pp         = (float*)(smem + QT * LK * 2 + 64);      // [12][16][16]

    int bid = blockIdx.x;
    int swz = (bid & 7) * 256 + (bid >> 3);   // bijective XCD swizzle (2048 % 8 == 0)
    int b = swz >> 7;
    int q0 = (swz & 127) * QT;

    int tid = threadIdx.x;
    int lane = tid & 63;
    int wave = tid >> 6;
    int lr = lane & 15, lg = lane >> 4;

    // Q fragments (B-operand of S^T = K·Q^T): lane holds Q[q0+lr][8*lg+i]
    bf16x8 qf0, qf1;
    {
        const unsigned short* qp = qb + ((int64_t)(b * LQ + q0 + lr)) * DH + 8 * lg;
        qf0 = *(const bf16x8*)qp;
        qf1 = *(const bf16x8*)(qp + 32);
    }

    // ---- phase 1: p = exp(clamp(QK^T/8)) (UNMASKED) -> LDS; pure L2 compute ----
    {
        const unsigned short* kpw =
            kb + (int64_t)b * LK * DH + (wave * 16 + lr) * DH + 8 * lg;
        bf16x8 kf0 = *(const bf16x8*)kpw;
        bf16x8 kf1 = *(const bf16x8*)(kpw + 32);
        #pragma unroll
        for (int kt = 0; kt < NIT; ++kt) {
            bf16x8 nk0, nk1;
            if (kt < NIT - 1) {
                const unsigned short* np = kpw + (int64_t)(kt + 1) * STRIP * DH;
                nk0 = *(const bf16x8*)np;
                nk1 = *(const bf16x8*)(np + 32);
            }
            f32x4 acc = {0.f, 0.f, 0.f, 0.f};
            acc = __builtin_amdgcn_mfma_f32_16x16x32_bf16(kf0, qf0, acc, 0, 0, 0);
            acc = __builtin_amdgcn_mfma_f32_16x16x32_bf16(kf1, qf1, acc, 0, 0, 0);
            // C[row=lg*4+j][col=lr] = S[q=lr][key = kt*STRIP + wave*16 + lg*4 + j]
            unsigned short eb[4];
            #pragma unroll
            for (int j = 0; j < 4; ++j) {
                float s = acc[j] * 0.125f;
                s = fminf(fmaxf(s, -15.0f), 15.0f);
                eb[j] = f2bf(__expf(s));
            }
            uint2 u;
            u.x = (uint32_t)eb[0] | ((uint32_t)eb[1] << 16);
            u.y = (uint32_t)eb[2] | ((uint32_t)eb[3] << 16);
            int c = kt * STRIP + wave * 16 + lg * 4;
            int byteoff = (lr * 4096 + c * 2) ^ ((lr & 7) << 4);
            *(uint2*)(smem + byteoff) = u;
            kf0 = nk0; kf1 = nk1;
        }
    }
    __syncthreads();

    // ---- phase 2: one wave per q-row. Stream mask row (max MLP), apply select,
    //      write masked bf16 back to LDS, reduce den, write attn row (nt). ----
    {
        int r = wave;
        int rowbase = r * 4096;
        int sw = (r & 7) << 4;
        int c0l = lane * 8;
        const float* mrow = mask + ((int64_t)(b * LQ + q0 + r)) * LK;

        float4 mk[8];
        #pragma unroll
        for (int i = 0; i < 4; ++i) {
            mk[2 * i]     = *(const float4*)(mrow + i * 512 + c0l);
            mk[2 * i + 1] = *(const float4*)(mrow + i * 512 + c0l + 4);
        }
        bf16x8 pv[4];
        #pragma unroll
        for (int i = 0; i < 4; ++i) {
            int byteoff = (rowbase + (i * 512 + c0l) * 2) ^ sw;
            pv[i] = *(const bf16x8*)(smem + byteoff);
        }
        float dsum = 0.f;
        uint32_t esave[16];
        #pragma unroll
        for (int i = 0; i < 4; ++i) {
            float mv[8] = {mk[2 * i].x, mk[2 * i].y, mk[2 * i].z, mk[2 * i].w,
                           mk[2 * i + 1].x, mk[2 * i + 1].y, mk[2 * i + 1].z,
                           mk[2 * i + 1].w};
            uint32_t packed[4];
            #pragma unroll
            for (int h = 0; h < 4; ++h) {
                unsigned short p0 = (unsigned short)pv[i][2 * h];
                unsigned short p1 = (unsigned short)pv[i][2 * h + 1];
                unsigned short e0 = (mv[2 * h] != 0.f) ? p0 : (unsigned short)0;
                unsigned short e1 = (mv[2 * h + 1] != 0.f) ? p1 : (unsigned short)0;
                dsum += bf2f(e0) + bf2f(e1);
                packed[h] = (uint32_t)e0 | ((uint32_t)e1 << 16);
                esave[i * 4 + h] = packed[h];
            }
            uint4 wb = {packed[0], packed[1], packed[2], packed[3]};
            int byteoff = (rowbase + (i * 512 + c0l) * 2) ^ sw;
            *(uint4*)(smem + byteoff) = wb;
        }
        // full 64-lane reduce
        dsum += __shfl_xor(dsum, 1);
        dsum += __shfl_xor(dsum, 2);
        dsum += __shfl_xor(dsum, 4);
        dsum += __shfl_xor(dsum, 8);
        dsum += __shfl_xor(dsum, 16);
        dsum += __shfl_xor(dsum, 32);
        float den = dsum + 1e-6f;
        if (lane == 0) denom_part[r] = den;
        float inv = 1.0f / den;
        float* ap = attn + ((int64_t)(b * LQ + q0 + r)) * LK;
        #pragma unroll
        for (int i = 0; i < 4; ++i) {
            f32x4 o0, o1;
            o0[0] = bf2f((unsigned short)(esave[i * 4 + 0] & 0xffff)) * inv;
            o0[1] = bf2f((unsigned short)(esave[i * 4 + 0] >> 16)) * inv;
            o0[2] = bf2f((unsigned short)(esave[i * 4 + 1] & 0xffff)) * inv;
            o0[3] = bf2f((unsigned short)(esave[i * 4 + 1] >> 16)) * inv;
            o1[0] = bf2f((unsigned short)(esave[i * 4 + 2] & 0xffff)) * inv;
            o1[1] = bf2f((unsigned short)(esave[i * 4 + 2] >> 16)) * inv;
            o1[2] = bf2f((unsigned short)(esave[i * 4 + 3] & 0xffff)) * inv;
            o1[3] = bf2f((unsigned short)(esave[i * 4 + 3] >> 16)) * inv;
            __builtin_nontemporal_store(o0, (f32x4*)(ap + i * 512 + c0l));
            __builtin_nontemporal_store(o1, (f32x4*)(ap + i * 512 + c0l + 4));
        }
    }
    __syncthreads();

    // ---- phase 3: PV; wave w -> col-tile (w&3)*16, K-quarter w>>2 ----
    f32x4 pacc = {0.f, 0.f, 0.f, 0.f};
    int cw = (wave & 3) * 16, kq = wave >> 2;
    {
        const unsigned short* vp =
            vtb + ((int64_t)(b * DH + cw + lr)) * LK + kq * 512 + 8 * lg;
        int rowbase = lr * 4096;
        int sw = (lr & 7) << 4;
        int kk0 = kq * 512;
        #pragma unroll 4
        for (int kk = 0; kk < 512; kk += 32) {
            int byteoff = (rowbase + (kk0 + kk + 8 * lg) * 2) ^ sw;
            bf16x8 ef = *(const bf16x8*)(smem + byteoff);
            bf16x8 vf = *(const bf16x8*)(vp + kk);
            pacc = __builtin_amdgcn_mfma_f32_16x16x32_bf16(ef, vf, pacc, 0, 0, 0);
        }
    }
    if (kq != 0) {
        #pragma unroll
        for (int j = 0; j < 4; ++j)
            pp[((kq - 1) * 4 + (wave & 3)) * 256 + (lg * 4 + j) * 16 + lr] = pacc[j];
    }
    __syncthreads();
    if (kq == 0) {
        int c4 = wave & 3;
        #pragma unroll
        for (int j = 0; j < 4; ++j) {
            int r = lg * 4 + j;
            float den = denom_part[r];
            float val = pacc[j] + pp[(c4) * 256 + r * 16 + lr] +
                        pp[(4 + c4) * 256 + r * 16 + lr] +
                        pp[(8 + c4) * 256 + r * 16 + lr];
            out[((int64_t)(b * LQ + q0 + r)) * DH + cw + lr] = val / den;
        }
    }
}

extern "C" void kernel_launch(void* const* d_in, const int* in_sizes, int n_in,
                              void* d_out, int out_size, void* d_ws, size_t ws_size,
                              hipStream_t stream) {
    const float* q    = (const float*)d_in[0];
    const float* k    = (const float*)d_in[1];
    const float* v    = (const float*)d_in[2];
    const float* mask = (const float*)d_in[3];
    float* out  = (float*)d_out;
    float* attn = out + (int64_t)NB * LQ * DH;

    unsigned short* qb  = (unsigned short*)d_ws;
    unsigned short* kb  = qb + (int64_t)NB * LQ * DH;
    unsigned short* vtb = kb + (int64_t)NB * LK * DH;

    (void)hipFuncSetAttribute((const void*)attn_kernel,
                              hipFuncAttributeMaxDynamicSharedMemorySize, 77888);

    convert_kernel<<<2560, 256, 0, stream>>>(q, k, v, qb, kb, vtb);
    attn_kernel<<<2048, 1024, 77888, stream>>>(qb, kb, vtb, mask, out, attn);
}